// Round 19
// baseline (196.654 us; speedup 1.0000x reference)
//
#include <hip/hip_runtime.h>
#include <hip/hip_bf16.h>
#include <hip/hip_fp16.h>

// Problem constants
#define B_      4
#define N_      2048
#define DIM_    128
#define HEADS_  8
#define HEAD_   128
#define INNER_  1024
#define QKV_    3072
#define EPS_    1e-5f
#define SCALE_  0.08838834764831845f   // HEAD^-0.5
// log2(10000)/64 for rope inv_freq = 2^(-i * this)
#define ROPE_C  0.20762050593046015f

typedef __attribute__((ext_vector_type(8))) short short8;   // 8 bf16 = 4 VGPRs
typedef __attribute__((ext_vector_type(4))) short short4v;  // 4 bf16 = 2 VGPRs
typedef __attribute__((ext_vector_type(4))) float f32x4;    // MFMA C/D 16x16
typedef __attribute__((ext_vector_type(16))) float f32x16;  // MFMA C/D 32x32

// Workspace (byte offsets) — R31 layout:
//  Q    [0,16M)   K [16M,32M)   Vt [32M,48M)        (bf16)
//  xnb  [96M,98M) bf16 [8192][128]
//  wqb  [98M,98.75M) bf16 [3072][128]
//  wob  [99M,99.25M) bf16 [128][1024]
//
// R31: k_proj FUSED into k_attn (R30 32x32-MFMA base, which measured equal
// to 16x16 with 0 bank conflicts and validated all layout derivations).
// R30 diagnosis: k_attn is instruction-issue-bound (VALU 54% + MFMA 30%
// ~saturated; duration invariant across 12 structural variants). Fusion
// removes the k_proj dispatch, the 32MB Ob round-trip, and k_attn's
// scattered Ob stores; adds 32 MFMA/wave (pipe at 30%) + fp32 atomics.
// k_prep pre-initializes out = bias each launch (idempotent under graph
// replay; atomic partial sums accumulate on top).

__device__ __forceinline__ unsigned short f2bf(float f) {
    unsigned u = __builtin_bit_cast(unsigned, f);
    u = (u + 0x7fffu + ((u >> 16) & 1u)) >> 16;
    return (unsigned short)u;
}
__device__ __forceinline__ float bf2f(unsigned short h) {
    unsigned u = ((unsigned)h) << 16;
    return __builtin_bit_cast(float, u);
}
__device__ __forceinline__ unsigned pk2(float a, float b) {
    return (unsigned)f2bf(a) | ((unsigned)f2bf(b) << 16);
}
// packed RNE fp32x4 -> bf16x4 via v_cvt_pk_bf16_f32 (HIP API); memcpy for the
// bit move because __hip_bfloat162 is not trivially copyable (R14 lesson).
__device__ __forceinline__ short4v pack4(const float* e) {
    __hip_bfloat162 h0 = __float22bfloat162_rn(make_float2(e[0], e[1]));
    __hip_bfloat162 h1 = __float22bfloat162_rn(make_float2(e[2], e[3]));
    uint2 u;
    __builtin_memcpy(&u.x, &h0, 4);
    __builtin_memcpy(&u.y, &h1, 4);
    return __builtin_bit_cast(short4v, u);
}

// ---------------------------------------------------------------------------
// K0: fused prep — LN (blocks 0..2047), w_qkv cvt (2048..2239),
// w_out cvt (2240..2303), out=bias init (2304..3327).
// ---------------------------------------------------------------------------
__global__ __launch_bounds__(256) void k_prep(
    const float* __restrict__ x, const float* __restrict__ g,
    const float* __restrict__ be, const float* __restrict__ w_qkv,
    const float* __restrict__ w_out, const float* __restrict__ bias,
    unsigned short* __restrict__ xnb, unsigned short* __restrict__ wqb,
    unsigned short* __restrict__ wob, float* __restrict__ out)
{
    const int bid = blockIdx.x;
    if (bid < 2048) {
        const int w = threadIdx.x >> 6, l = threadIdx.x & 63;
        const int row = bid * 4 + w;
        float2 v = *(const float2*)(x + (size_t)row * 128 + l * 2);
        float s = v.x + v.y, s2 = v.x * v.x + v.y * v.y;
#pragma unroll
        for (int off = 1; off < 64; off <<= 1) {
            s  += __shfl_xor(s, off);
            s2 += __shfl_xor(s2, off);
        }
        float mu = s * (1.f / 128.f);
        float var = s2 * (1.f / 128.f) - mu * mu;
        float rs = rsqrtf(var + EPS_);
        float2 gg = *(const float2*)(g + l * 2);
        float2 bb = *(const float2*)(be + l * 2);
        float ox = (v.x - mu) * rs * gg.x + bb.x;
        float oy = (v.y - mu) * rs * gg.y + bb.y;
        *(unsigned*)(xnb + (size_t)row * 128 + l * 2) = pk2(ox, oy);
    } else if (bid < 2240) {
        size_t i = ((size_t)(bid - 2048) * 256 + threadIdx.x) * 8;
        float4 f0 = *(const float4*)(w_qkv + i), f1 = *(const float4*)(w_qkv + i + 4);
        uint4 u = { pk2(f0.x, f0.y), pk2(f0.z, f0.w), pk2(f1.x, f1.y), pk2(f1.z, f1.w) };
        *(uint4*)(wqb + i) = u;
    } else if (bid < 2304) {
        size_t i = ((size_t)(bid - 2240) * 256 + threadIdx.x) * 8;
        float4 f0 = *(const float4*)(w_out + i), f1 = *(const float4*)(w_out + i + 4);
        uint4 u = { pk2(f0.x, f0.y), pk2(f0.z, f0.w), pk2(f1.x, f1.y), pk2(f1.z, f1.w) };
        *(uint4*)(wob + i) = u;
    } else {
        // out = bias broadcast (8192 rows x 128). i is a multiple of 4;
        // (i & 127) = column of element i.
        size_t i = ((size_t)(bid - 2304) * 256 + threadIdx.x) * 4;
        float4 bb = *(const float4*)(bias + (i & 127));
        *(float4*)(out + i) = bb;
    }
}

// ---------------------------------------------------------------------------
// K1: fused QKV GEMM + rope + scatter. M=128 x N=128, K=128 one-shot.
// Grid (64, 24). UNPADDED XOR-swizzled LDS (2x32KB = 64KB -> 2 blk/CU).
// V epilogue permutation = swap bits 2<->3 of local n within each 16-seq
// block (R30-validated; matches k_attn's lane-local PV repack).
// ---------------------------------------------------------------------------
__global__ __launch_bounds__(256) void k_qkvf(
    const unsigned short* __restrict__ xnb, const unsigned short* __restrict__ wb,
    unsigned short* __restrict__ Q, unsigned short* __restrict__ K,
    unsigned short* __restrict__ Vt)
{
    __shared__ unsigned short lA[128 * 128];
    __shared__ unsigned short lB[128 * 128];
    const int t = threadIdx.x;
    const int wv = t >> 6, l = t & 63;
    const int lm = l & 15, quad = l >> 4;
    const int row0 = blockIdx.x * 128;
    const int by   = blockIdx.y;
    const int e0   = by * 128;

#pragma unroll
    for (int i = 0; i < 8; ++i) {
        int c = t + 256 * i;  int r = c >> 4, c8 = c & 15;
        int sc = (c8 ^ (r & 7)) * 8;
        *(uint4*)&lA[r * 128 + sc] =
            *(const uint4*)(xnb + (size_t)(row0 + r) * 128 + c8 * 8);
        *(uint4*)&lB[r * 128 + sc] =
            *(const uint4*)(wb + (size_t)(e0 + r) * 128 + c8 * 8);
    }
    __syncthreads();

    short8 af[2][4];
#pragma unroll
    for (int mt = 0; mt < 2; ++mt)
#pragma unroll
        for (int ks = 0; ks < 4; ++ks) {
            int r = wv * 32 + mt * 16 + lm;
            af[mt][ks] = *(short8*)&lA[r * 128 + (((ks * 4 + quad) ^ (r & 7)) << 3)];
        }

    f32x4 acc[2][8];
#pragma unroll
    for (int mt = 0; mt < 2; ++mt)
#pragma unroll
        for (int ct = 0; ct < 8; ++ct) acc[mt][ct] = (f32x4){0.f, 0.f, 0.f, 0.f};
#pragma unroll
    for (int ks = 0; ks < 4; ++ks) {
#pragma unroll
        for (int ct = 0; ct < 8; ++ct) {
            int r = ct * 16 + lm;
            short8 b = *(short8*)&lB[r * 128 + (((ks * 4 + quad) ^ (r & 7)) << 3)];
            acc[0][ct] = __builtin_amdgcn_mfma_f32_16x16x32_bf16(af[0][ks], b, acc[0][ct], 0, 0, 0);
            acc[1][ct] = __builtin_amdgcn_mfma_f32_16x16x32_bf16(af[1][ks], b, acc[1][ct], 0, 0, 0);
        }
    }
    __syncthreads();

    const int b  = row0 >> 11;           // batch
    const int n0 = row0 & (N_ - 1);      // n within batch (block-uniform)
    const int h  = by & 7;
    const int bh = b * 8 + h;

    if (by < 16) {
        // ---- Q or K: stage row-major (swizzled), rope, scatter ----
#pragma unroll
        for (int mt = 0; mt < 2; ++mt)
#pragma unroll
            for (int ct = 0; ct < 8; ++ct)
#pragma unroll
                for (int r = 0; r < 4; ++r) {
                    int row = wv * 32 + mt * 16 + quad * 4 + r;
                    int chunk = ct * 2 + (lm >> 3);
                    lA[row * 128 + ((chunk ^ (row & 7)) << 3) + (lm & 7)] =
                        f2bf(acc[mt][ct][r]);
                }
        __syncthreads();

        const int r_loc = t >> 1, half = t & 1;
        const int n = n0 + r_loc;
        unsigned short* dst = (by < 8 ? Q : K) +
            ((size_t)bh * N_ + n) * HEAD_ + half * 64;
        const bool dorope = (n != N_ - 1);
#pragma unroll
        for (int j = 0; j < 8; ++j) {
            short8 vv = *(short8*)&lA[r_loc * 128 + (((half * 8 + j) ^ (r_loc & 7)) << 3)];
            if (dorope) {
                unsigned short* pv = (unsigned short*)&vv;
#pragma unroll
                for (int p = 0; p < 4; ++p) {
                    int i0 = half * 32 + j * 4 + p;
                    float invf = exp2f(-(float)i0 * ROPE_C);
                    float th = (float)n * invf;
                    float cs = __cosf(th), sn = __sinf(th);
                    float e = bf2f(pv[2 * p]), o = bf2f(pv[2 * p + 1]);
                    pv[2 * p]     = f2bf(e * cs - o * sn);
                    pv[2 * p + 1] = f2bf(o * cs + e * sn);
                }
            }
            *(short8*)(dst + j * 8) = vv;
        }
    } else {
        // ---- V: stage transposed + permuted (swizzled), linear copy ----
        // local n = wv*32 + mt*16 + quad*4 + r
        // n' = swap bits 2<->3: chunk = wv*4+mt*2+(quad&1), off = (quad>>1)*4+r
#pragma unroll
        for (int mt = 0; mt < 2; ++mt)
#pragma unroll
            for (int ct = 0; ct < 8; ++ct)
#pragma unroll
                for (int r = 0; r < 4; ++r) {
                    int row = ct * 16 + lm;                     // d
                    int chunk = wv * 4 + mt * 2 + (quad & 1);
                    int off   = (quad >> 1) * 4 + r;
                    lA[row * 128 + ((chunk ^ (row & 7)) << 3) + off] =
                        f2bf(acc[mt][ct][r]);
                }
        __syncthreads();

        const int d = t >> 1, half = t & 1;
        unsigned short* dst = Vt + ((size_t)bh * HEAD_ + d) * N_ + n0 + half * 64;
#pragma unroll
        for (int j = 0; j < 8; ++j)
            *(short8*)(dst + j * 8) =
                *(short8*)&lA[d * 128 + (((half * 8 + j) ^ (d & 7)) << 3)];
    }
}

// ---------------------------------------------------------------------------
// K3: flash attention + fused output projection (R31).
// Main loop: R30 32x32x16-MFMA structure verbatim (validated, 0 conflicts).
// Epilogue: normalize O -> bf16 -> LDS (A-fragment layout) -> 32 MFMA
// against wob head-slice -> fp32 atomicAdd into out (pre-inited to bias).
// ---------------------------------------------------------------------------
__global__ __launch_bounds__(256) void k_attn(
    const unsigned short* __restrict__ Q, const unsigned short* __restrict__ K,
    const unsigned short* __restrict__ Vt, const unsigned short* __restrict__ wob,
    float* __restrict__ out)
{
    __shared__ unsigned short pool[64 * 136 + 128 * 72];
    unsigned short* lK = pool;                 // [64][136]
    unsigned short* lV = pool + 64 * 136;      // [128][72]

    const int t = threadIdx.x;
    const int w = t >> 6, l = t & 63;
    const int q32 = l & 31, hi = l >> 5;
    const int bid = blockIdx.x;
    const int bh = bid & 31;
    const int qt = bid >> 5;
    const int n0 = qt * 128;
    const unsigned short* Qb = Q  + (size_t)bh * N_ * HEAD_;
    const unsigned short* Kb = K  + (size_t)bh * N_ * HEAD_;
    const unsigned short* Vb = Vt + (size_t)bh * N_ * HEAD_;

    // Q fragments (B operand: col=q32, kdim rows hi*8+j), 8 k-chunks of 16
    short8 aq[8];
    {
        const unsigned short* qp =
            Qb + (size_t)(n0 + w * 32 + q32) * 128 + hi * 8;
#pragma unroll
        for (int kc = 0; kc < 8; ++kc)
            aq[kc] = *(const short8*)(qp + kc * 16);
    }

    f32x16 Oa[4];
#pragma unroll
    for (int i = 0; i < 4; ++i)
        Oa[i] = (f32x16){0.f,0.f,0.f,0.f,0.f,0.f,0.f,0.f,
                         0.f,0.f,0.f,0.f,0.f,0.f,0.f,0.f};
    float ps = 0.f;
    const float C1 = SCALE_ * 1.44269504f;
    const float C0 = -23.08312f;     // -16*log2(e); const shift is exact

    short8 kr[4], vr[4];
#pragma unroll
    for (int i = 0; i < 4; ++i) {
        int c = t + 256 * i;
        kr[i] = *(const short8*)(Kb + ((size_t)(c >> 4)) * 128 + (c & 15) * 8);
        vr[i] = *(const short8*)(Vb + (size_t)(c >> 3) * N_ + (c & 7) * 8);
    }

    for (int jt = 0; jt < 32; ++jt) {
        __syncthreads();
#pragma unroll
        for (int i = 0; i < 4; ++i) {
            int c = t + 256 * i;
            *(short8*)&lK[(c >> 4) * 136 + (c & 15) * 8] = kr[i];
            *(short8*)&lV[(c >> 3) * 72  + (c & 7)  * 8] = vr[i];
        }
        __syncthreads();
        if (jt < 31) {
#pragma unroll
            for (int i = 0; i < 4; ++i) {
                int c = t + 256 * i;
                kr[i] = *(const short8*)(Kb + ((size_t)((jt + 1) * 64 + (c >> 4))) * 128 + (c & 15) * 8);
                vr[i] = *(const short8*)(Vb + (size_t)(c >> 3) * N_ + (jt + 1) * 64 + (c & 7) * 8);
            }
        }

        // ---- QK^T: two 32x32 S^T tiles ----
        f32x16 st0 = (f32x16){0.f,0.f,0.f,0.f,0.f,0.f,0.f,0.f,
                              0.f,0.f,0.f,0.f,0.f,0.f,0.f,0.f};
        f32x16 st1 = st0;
#pragma unroll
        for (int kc = 0; kc < 8; ++kc) {
            short8 kf0 = *(short8*)&lK[q32 * 136 + kc * 16 + hi * 8];
            short8 kf1 = *(short8*)&lK[(32 + q32) * 136 + kc * 16 + hi * 8];
            st0 = __builtin_amdgcn_mfma_f32_32x32x16_bf16(kf0, aq[kc], st0, 0, 0, 0);
            st1 = __builtin_amdgcn_mfma_f32_32x32x16_bf16(kf1, aq[kc], st1, 0, 0, 0);
        }

        // ---- exp + partial sums + pack PV A-fragments (lane-local) ----
        short8 pa[4];
#pragma unroll
        for (int T = 0; T < 2; ++T) {
#pragma unroll
            for (int g = 0; g < 2; ++g) {
                float e[8];
#pragma unroll
                for (int j = 0; j < 8; ++j) {
                    float s = T ? st1[8 * g + j] : st0[8 * g + j];
                    e[j] = exp2f(s * C1 + C0);
                    ps += e[j];
                }
                short4v lo = pack4(e);
                short4v hh = pack4(e + 4);
                pa[T * 2 + g] = __builtin_shufflevector(lo, hh, 0, 1, 2, 3, 4, 5, 6, 7);
            }
        }

        // ---- PV: 4 d-tiles x 4 k-chunks ----
#pragma unroll
        for (int dt = 0; dt < 4; ++dt) {
            const int d = dt * 32 + q32;
#pragma unroll
            for (int kc = 0; kc < 4; ++kc) {
                short8 bv = *(short8*)&lV[d * 72 + kc * 16 + hi * 8];
                Oa[dt] = __builtin_amdgcn_mfma_f32_32x32x16_bf16(pa[kc], bv, Oa[dt], 0, 0, 0);
            }
        }
    }

    // ---- normalize ----
    ps += __shfl_xor(ps, 32);          // total for q = q32 (both hi lanes)
    float inv = 1.f / ps;
    float ilq[16];
#pragma unroll
    for (int m = 0; m < 4; ++m)
#pragma unroll
        for (int r = 0; r < 4; ++r)
            ilq[m * 4 + r] = __shfl(inv, 4 * hi + r + 8 * m);

    // ---- stage normalized O (bf16) into pool in A-fragment layout ----
    __syncthreads();                   // all lV reads of last tile done
    unsigned short* Ot = pool + w * 4352;   // per-wave [32][136]
#pragma unroll
    for (int dt = 0; dt < 4; ++dt) {
        const int d = dt * 32 + q32;
#pragma unroll
        for (int m = 0; m < 4; ++m)
#pragma unroll
            for (int r = 0; r < 4; ++r) {
                int ql = 4 * hi + r + 8 * m;
                Ot[ql * 136 + d] = f2bf(Oa[dt][m * 4 + r] * ilq[m * 4 + r]);
            }
    }
    __syncthreads();

    // ---- fused projection: D[q][e] += O[q][:] . wob[e][h*128+:] ----
    short8 aO[8];
#pragma unroll
    for (int kc = 0; kc < 8; ++kc)
        aO[kc] = *(short8*)&Ot[q32 * 136 + kc * 16 + hi * 8];

    const int b = bh >> 3, h = bh & 7;
    float* outB = out + ((size_t)b * N_ + n0 + w * 32) * 128;

#pragma unroll
    for (int et = 0; et < 4; ++et) {
        f32x16 pc = (f32x16){0.f,0.f,0.f,0.f,0.f,0.f,0.f,0.f,
                             0.f,0.f,0.f,0.f,0.f,0.f,0.f,0.f};
#pragma unroll
        for (int kc = 0; kc < 8; ++kc) {
            short8 wB = *(const short8*)(
                wob + (size_t)(et * 32 + q32) * 1024 + h * 128 + kc * 16 + hi * 8);
            pc = __builtin_amdgcn_mfma_f32_32x32x16_bf16(aO[kc], wB, pc, 0, 0, 0);
        }
#pragma unroll
        for (int m = 0; m < 4; ++m)
#pragma unroll
            for (int r = 0; r < 4; ++r) {
                int ql = 4 * hi + r + 8 * m;
                unsafeAtomicAdd(outB + (size_t)ql * 128 + et * 32 + q32,
                                pc[m * 4 + r]);
            }
    }
}

// ---------------------------------------------------------------------------
extern "C" void kernel_launch(void* const* d_in, const int* in_sizes, int n_in,
                              void* d_out, int out_size, void* d_ws, size_t ws_size,
                              hipStream_t stream) {
    const float* x      = (const float*)d_in[0];
    const float* gamma  = (const float*)d_in[1];
    const float* beta   = (const float*)d_in[2];
    const float* w_qkv  = (const float*)d_in[3];
    const float* w_out  = (const float*)d_in[4];
    const float* b_out  = (const float*)d_in[5];
    float* out = (float*)d_out;
    char* wsb = (char*)d_ws;
    unsigned short* Q    = (unsigned short*)(wsb);
    unsigned short* K    = (unsigned short*)(wsb + (16ull << 20));
    unsigned short* Vt   = (unsigned short*)(wsb + (32ull << 20));
    unsigned short* xnb  = (unsigned short*)(wsb + (96ull << 20));
    unsigned short* wqb  = (unsigned short*)(wsb + (98ull << 20));
    unsigned short* wob  = (unsigned short*)(wsb + (99ull << 20));

    k_prep <<<dim3(3328),    256, 0, stream>>>(x, gamma, beta, w_qkv, w_out,
                                               b_out, xnb, wqb, wob, out);
    k_qkvf <<<dim3(64, 24),  256, 0, stream>>>(xnb, wqb, Q, K, Vt);
    k_attn <<<dim3(512),     256, 0, stream>>>(Q, K, Vt, wob, out);
}

// Round 20
// 188.158 us; speedup vs baseline: 1.0452x; 1.0452x over previous
//
#include <hip/hip_runtime.h>
#include <hip/hip_bf16.h>
#include <hip/hip_fp16.h>

// Problem constants
#define B_      4
#define N_      2048
#define DIM_    128
#define HEADS_  8
#define HEAD_   128
#define INNER_  1024
#define QKV_    3072
#define EPS_    1e-5f
#define SCALE_  0.08838834764831845f   // HEAD^-0.5
// log2(10000)/64 for rope inv_freq = 2^(-i * this)
#define ROPE_C  0.20762050593046015f

typedef __attribute__((ext_vector_type(8))) short short8;   // 8 bf16 = 4 VGPRs
typedef __attribute__((ext_vector_type(4))) short short4v;  // 4 bf16 = 2 VGPRs
typedef __attribute__((ext_vector_type(4))) float f32x4;    // MFMA C/D

// Workspace (byte offsets) — R32 = R29/R22 VERBATIM (best measured: 188.7us):
//  Q    [0,16M)   K [16M,32M)   Vt [32M,48M)        (bf16)
//  Ob   [48M,64M) bf16 [B][N][INNER]
//  xnb  [96M,98M) bf16 [8192][128]
//  wqb  [98M,98.75M) bf16 [3072][128]
//  wob  [99M,99.25M) bf16 [128][1024]
//
// R32 (final): locks the session optimum. R31 post-mortem: proj-fusion was
// net-negative (+8us: epilogue atomics/restage cost > k_proj's ~9us).
// Session ledger: k_attn invariant at ~99.5us across 13 structural
// variants (issue/latency-bound at 2 blk/CU); chain ~89us rejected all
// consolidations. R29 config = measured optimum.

__device__ __forceinline__ unsigned short f2bf(float f) {
    unsigned u = __builtin_bit_cast(unsigned, f);
    u = (u + 0x7fffu + ((u >> 16) & 1u)) >> 16;
    return (unsigned short)u;
}
__device__ __forceinline__ float bf2f(unsigned short h) {
    unsigned u = ((unsigned)h) << 16;
    return __builtin_bit_cast(float, u);
}
__device__ __forceinline__ unsigned pk2(float a, float b) {
    return (unsigned)f2bf(a) | ((unsigned)f2bf(b) << 16);
}
// packed RNE fp32x4 -> bf16x4 via v_cvt_pk_bf16_f32 (HIP API); memcpy for the
// bit move because __hip_bfloat162 is not trivially copyable (R14 lesson).
__device__ __forceinline__ short4v pack4(const float* e) {
    __hip_bfloat162 h0 = __float22bfloat162_rn(make_float2(e[0], e[1]));
    __hip_bfloat162 h1 = __float22bfloat162_rn(make_float2(e[2], e[3]));
    uint2 u;
    __builtin_memcpy(&u.x, &h0, 4);
    __builtin_memcpy(&u.y, &h1, 4);
    return __builtin_bit_cast(short4v, u);
}

// ---------------------------------------------------------------------------
// K0: fused prep — LN (blocks 0..2047), w_qkv cvt (2048..2239),
// w_out cvt (2240..2303). One launch instead of three.
// ---------------------------------------------------------------------------
__global__ __launch_bounds__(256) void k_prep(
    const float* __restrict__ x, const float* __restrict__ g,
    const float* __restrict__ be, const float* __restrict__ w_qkv,
    const float* __restrict__ w_out, unsigned short* __restrict__ xnb,
    unsigned short* __restrict__ wqb, unsigned short* __restrict__ wob)
{
    const int bid = blockIdx.x;
    if (bid < 2048) {
        const int w = threadIdx.x >> 6, l = threadIdx.x & 63;
        const int row = bid * 4 + w;
        float2 v = *(const float2*)(x + (size_t)row * 128 + l * 2);
        float s = v.x + v.y, s2 = v.x * v.x + v.y * v.y;
#pragma unroll
        for (int off = 1; off < 64; off <<= 1) {
            s  += __shfl_xor(s, off);
            s2 += __shfl_xor(s2, off);
        }
        float mu = s * (1.f / 128.f);
        float var = s2 * (1.f / 128.f) - mu * mu;
        float rs = rsqrtf(var + EPS_);
        float2 gg = *(const float2*)(g + l * 2);
        float2 bb = *(const float2*)(be + l * 2);
        float ox = (v.x - mu) * rs * gg.x + bb.x;
        float oy = (v.y - mu) * rs * gg.y + bb.y;
        *(unsigned*)(xnb + (size_t)row * 128 + l * 2) = pk2(ox, oy);
    } else if (bid < 2240) {
        size_t i = ((size_t)(bid - 2048) * 256 + threadIdx.x) * 8;
        float4 f0 = *(const float4*)(w_qkv + i), f1 = *(const float4*)(w_qkv + i + 4);
        uint4 u = { pk2(f0.x, f0.y), pk2(f0.z, f0.w), pk2(f1.x, f1.y), pk2(f1.z, f1.w) };
        *(uint4*)(wqb + i) = u;
    } else {
        size_t i = ((size_t)(bid - 2240) * 256 + threadIdx.x) * 8;
        float4 f0 = *(const float4*)(w_out + i), f1 = *(const float4*)(w_out + i + 4);
        uint4 u = { pk2(f0.x, f0.y), pk2(f0.z, f0.w), pk2(f1.x, f1.y), pk2(f1.z, f1.w) };
        *(uint4*)(wob + i) = u;
    }
}

// ---------------------------------------------------------------------------
// K1: fused QKV GEMM + rope + scatter. M=128 x N=128, K=128 one-shot.
// Grid (64, 24). UNPADDED XOR-swizzled LDS (2x32KB = 64KB -> 2 blk/CU).
// Element layout: lX[r][(chunk ^ (r&7))*8 + within], chunk = col>>3.
// ---------------------------------------------------------------------------
__global__ __launch_bounds__(256) void k_qkvf(
    const unsigned short* __restrict__ xnb, const unsigned short* __restrict__ wb,
    unsigned short* __restrict__ Q, unsigned short* __restrict__ K,
    unsigned short* __restrict__ Vt)
{
    __shared__ unsigned short lA[128 * 128];
    __shared__ unsigned short lB[128 * 128];
    const int t = threadIdx.x;
    const int wv = t >> 6, l = t & 63;
    const int lm = l & 15, quad = l >> 4;
    const int row0 = blockIdx.x * 128;
    const int by   = blockIdx.y;
    const int e0   = by * 128;

#pragma unroll
    for (int i = 0; i < 8; ++i) {
        int c = t + 256 * i;  int r = c >> 4, c8 = c & 15;
        int sc = (c8 ^ (r & 7)) * 8;
        *(uint4*)&lA[r * 128 + sc] =
            *(const uint4*)(xnb + (size_t)(row0 + r) * 128 + c8 * 8);
        *(uint4*)&lB[r * 128 + sc] =
            *(const uint4*)(wb + (size_t)(e0 + r) * 128 + c8 * 8);
    }
    __syncthreads();

    short8 af[2][4];
#pragma unroll
    for (int mt = 0; mt < 2; ++mt)
#pragma unroll
        for (int ks = 0; ks < 4; ++ks) {
            int r = wv * 32 + mt * 16 + lm;
            af[mt][ks] = *(short8*)&lA[r * 128 + (((ks * 4 + quad) ^ (r & 7)) << 3)];
        }

    f32x4 acc[2][8];
#pragma unroll
    for (int mt = 0; mt < 2; ++mt)
#pragma unroll
        for (int ct = 0; ct < 8; ++ct) acc[mt][ct] = (f32x4){0.f, 0.f, 0.f, 0.f};
#pragma unroll
    for (int ks = 0; ks < 4; ++ks) {
#pragma unroll
        for (int ct = 0; ct < 8; ++ct) {
            int r = ct * 16 + lm;
            short8 b = *(short8*)&lB[r * 128 + (((ks * 4 + quad) ^ (r & 7)) << 3)];
            acc[0][ct] = __builtin_amdgcn_mfma_f32_16x16x32_bf16(af[0][ks], b, acc[0][ct], 0, 0, 0);
            acc[1][ct] = __builtin_amdgcn_mfma_f32_16x16x32_bf16(af[1][ks], b, acc[1][ct], 0, 0, 0);
        }
    }
    __syncthreads();

    const int b  = row0 >> 11;           // batch
    const int n0 = row0 & (N_ - 1);      // n within batch (block-uniform)
    const int h  = by & 7;
    const int bh = b * 8 + h;

    if (by < 16) {
        // ---- Q or K: stage row-major (swizzled), rope, scatter ----
#pragma unroll
        for (int mt = 0; mt < 2; ++mt)
#pragma unroll
            for (int ct = 0; ct < 8; ++ct)
#pragma unroll
                for (int r = 0; r < 4; ++r) {
                    int row = wv * 32 + mt * 16 + quad * 4 + r;
                    int chunk = ct * 2 + (lm >> 3);
                    lA[row * 128 + ((chunk ^ (row & 7)) << 3) + (lm & 7)] =
                        f2bf(acc[mt][ct][r]);
                }
        __syncthreads();

        const int r_loc = t >> 1, half = t & 1;
        const int n = n0 + r_loc;
        unsigned short* dst = (by < 8 ? Q : K) +
            ((size_t)bh * N_ + n) * HEAD_ + half * 64;
        const bool dorope = (n != N_ - 1);
#pragma unroll
        for (int j = 0; j < 8; ++j) {
            short8 vv = *(short8*)&lA[r_loc * 128 + (((half * 8 + j) ^ (r_loc & 7)) << 3)];
            if (dorope) {
                unsigned short* pv = (unsigned short*)&vv;
#pragma unroll
                for (int p = 0; p < 4; ++p) {
                    int i0 = half * 32 + j * 4 + p;
                    float invf = exp2f(-(float)i0 * ROPE_C);
                    float th = (float)n * invf;
                    float cs = __cosf(th), sn = __sinf(th);
                    float e = bf2f(pv[2 * p]), o = bf2f(pv[2 * p + 1]);
                    pv[2 * p]     = f2bf(e * cs - o * sn);
                    pv[2 * p + 1] = f2bf(o * cs + e * sn);
                }
            }
            *(short8*)(dst + j * 8) = vv;
        }
    } else {
        // ---- V: stage transposed + permuted (swizzled), linear copy ----
        // local n = wv*32 + mt*16 + quad*4 + r  ->  n' = wv*32 + quad*8 + mt*4 + r
#pragma unroll
        for (int mt = 0; mt < 2; ++mt)
#pragma unroll
            for (int ct = 0; ct < 8; ++ct)
#pragma unroll
                for (int r = 0; r < 4; ++r) {
                    int row = ct * 16 + lm;            // d
                    int chunk = wv * 4 + quad;         // n' chunk
                    lA[row * 128 + ((chunk ^ (row & 7)) << 3) + mt * 4 + r] =
                        f2bf(acc[mt][ct][r]);
                }
        __syncthreads();

        const int d = t >> 1, half = t & 1;
        unsigned short* dst = Vt + ((size_t)bh * HEAD_ + d) * N_ + n0 + half * 64;
#pragma unroll
        for (int j = 0; j < 8; ++j)
            *(short8*)(dst + j * 8) =
                *(short8*)&lA[d * 128 + (((half * 8 + j) ^ (d & 7)) << 3)];
    }
}

// ---------------------------------------------------------------------------
// K3: flash attention — R15 structure verbatim (measured best ~100us).
// Single buffer, 2 barriers/jt, reg staging, padded LDS (34,816B, 2 blk/CU).
// ---------------------------------------------------------------------------
__global__ __launch_bounds__(256) void k_attn(
    const unsigned short* __restrict__ Q, const unsigned short* __restrict__ K,
    const unsigned short* __restrict__ Vt, unsigned short* __restrict__ Ob)
{
    __shared__ unsigned short lK[64 * 136];
    __shared__ unsigned short lV[128 * 68];

    const int t = threadIdx.x;
    const int w = t >> 6, l = t & 63;
    const int lm = l & 15, quad = l >> 4;
    const int bid = blockIdx.x;
    const int bh = bid & 31;
    const int qt = bid >> 5;
    const int n0 = qt * 128;
    const unsigned short* Qb = Q  + (size_t)bh * N_ * HEAD_;
    const unsigned short* Kb = K  + (size_t)bh * N_ * HEAD_;
    const unsigned short* Vb = Vt + (size_t)bh * N_ * HEAD_;

    short8 aq[2][4];
#pragma unroll
    for (int tt = 0; tt < 2; ++tt) {
        const unsigned short* qp =
            Qb + ((size_t)(n0 + tt * 64 + w * 16 + lm)) * 128 + quad * 8;
#pragma unroll
        for (int ks = 0; ks < 4; ++ks)
            aq[tt][ks] = *(const short8*)(qp + ks * 32);
    }

    f32x4 Oa[2][8];
#pragma unroll
    for (int tt = 0; tt < 2; ++tt)
#pragma unroll
        for (int i = 0; i < 8; ++i) Oa[tt][i] = (f32x4){0.f, 0.f, 0.f, 0.f};
    float ps0 = 0.f, ps1 = 0.f;
    const float C1 = SCALE_ * 1.44269504f;
    const float C0 = -23.08312f;

    short8 kr[4], vr[4];
#pragma unroll
    for (int i = 0; i < 4; ++i) {
        int c = t + 256 * i;
        kr[i] = *(const short8*)(Kb + ((size_t)(c >> 4)) * 128 + (c & 15) * 8);
        vr[i] = *(const short8*)(Vb + (size_t)(c >> 3) * N_ + (c & 7) * 8);
    }

    for (int jt = 0; jt < 32; ++jt) {
        __syncthreads();
#pragma unroll
        for (int i = 0; i < 4; ++i) {
            int c = t + 256 * i;
            *(short8*)&lK[(c >> 4) * 136 + (c & 15) * 8] = kr[i];
            *(short8*)&lV[(c >> 3) * 68  + (c & 7)  * 8] = vr[i];
        }
        __syncthreads();
        if (jt < 31) {
#pragma unroll
            for (int i = 0; i < 4; ++i) {
                int c = t + 256 * i;
                kr[i] = *(const short8*)(Kb + ((size_t)((jt + 1) * 64 + (c >> 4))) * 128 + (c & 15) * 8);
                vr[i] = *(const short8*)(Vb + (size_t)(c >> 3) * N_ + (jt + 1) * 64 + (c & 7) * 8);
            }
        }

        short4v pf0[4], pf1[4];
#pragma unroll
        for (int nb = 0; nb < 4; ++nb) {
            f32x4 st0 = (f32x4){0.f, 0.f, 0.f, 0.f};
            f32x4 st1 = (f32x4){0.f, 0.f, 0.f, 0.f};
#pragma unroll
            for (int ks = 0; ks < 4; ++ks) {
                short8 kf = *(short8*)&lK[(nb * 16 + lm) * 136 + ks * 32 + quad * 8];
                st0 = __builtin_amdgcn_mfma_f32_16x16x32_bf16(kf, aq[0][ks], st0, 0, 0, 0);
                st1 = __builtin_amdgcn_mfma_f32_16x16x32_bf16(kf, aq[1][ks], st1, 0, 0, 0);
            }
            float e0[4], e1[4];
#pragma unroll
            for (int r = 0; r < 4; ++r) {
                e0[r] = exp2f(st0[r] * C1 + C0);
                e1[r] = exp2f(st1[r] * C1 + C0);
                ps0 += e0[r];  ps1 += e1[r];
            }
            pf0[nb] = pack4(e0);
            pf1[nb] = pack4(e1);
        }

#pragma unroll
        for (int c2 = 0; c2 < 2; ++c2) {
            short8 ap0 = __builtin_shufflevector(pf0[2 * c2], pf0[2 * c2 + 1],
                                                 0, 1, 2, 3, 4, 5, 6, 7);
            short8 ap1 = __builtin_shufflevector(pf1[2 * c2], pf1[2 * c2 + 1],
                                                 0, 1, 2, 3, 4, 5, 6, 7);
#pragma unroll
            for (int nb8 = 0; nb8 < 8; ++nb8) {
                short8 bv = *(short8*)&lV[(nb8 * 16 + lm) * 68 + c2 * 32 + quad * 8];
                Oa[0][nb8] = __builtin_amdgcn_mfma_f32_16x16x32_bf16(ap0, bv, Oa[0][nb8], 0, 0, 0);
                Oa[1][nb8] = __builtin_amdgcn_mfma_f32_16x16x32_bf16(ap1, bv, Oa[1][nb8], 0, 0, 0);
            }
        }
    }

    ps0 += __shfl_xor(ps0, 16);  ps0 += __shfl_xor(ps0, 32);
    ps1 += __shfl_xor(ps1, 16);  ps1 += __shfl_xor(ps1, 32);

    const int b = bh >> 3, h = bh & 7;
#pragma unroll
    for (int tt = 0; tt < 2; ++tt)
#pragma unroll
        for (int r = 0; r < 4; ++r) {
            float lsum = __shfl(tt == 0 ? ps0 : ps1, (l & 48) | (quad * 4 + r));
            float il = 1.f / lsum;
            int n = n0 + tt * 64 + w * 16 + quad * 4 + r;
            unsigned short* op = Ob + ((size_t)b * N_ + n) * INNER_ + h * HEAD_ + lm;
#pragma unroll
            for (int nb8 = 0; nb8 < 8; ++nb8)
                op[nb8 * 16] = f2bf(Oa[tt][nb8][r] * il);
        }
}

// ---------------------------------------------------------------------------
// K4: output projection. BM=32 (grid (256,2) = 512 blocks -> 2 blk/CU).
// Per block: 32x64 out tile, K=1024. Wave wv: row tile rt=wv&1, col half
// ch=wv>>1, 2 MFMA tiles. lCf aliases lA (26KB total LDS -> 32KB granule).
// ---------------------------------------------------------------------------
__global__ __launch_bounds__(256) void k_proj(
    const unsigned short* __restrict__ Ob, const unsigned short* __restrict__ wob,
    const float* __restrict__ bias, float* __restrict__ out)
{
    __shared__ unsigned short lA[32 * 136];
    __shared__ unsigned short lB[64 * 136];
    float* lCf = (float*)lA;                 // 32*68 floats = 8704B = sizeof lA
    const int t = threadIdx.x;
    const int wv = t >> 6, l = t & 63;
    const int lm = l & 15, quad = l >> 4;
    const int rt = wv & 1, ch = wv >> 1;
    const int row0 = blockIdx.x * 32;
    const int e0   = blockIdx.y * 64;

    f32x4 acc[2];
#pragma unroll
    for (int ct = 0; ct < 2; ++ct) acc[ct] = (f32x4){0.f, 0.f, 0.f, 0.f};

    for (int kt = 0; kt < 8; ++kt) {
        __syncthreads();
#pragma unroll
        for (int i = 0; i < 2; ++i) {
            int c = t + 256 * i;  int r = c >> 4, c8 = c & 15;
            *(uint4*)&lA[r * 136 + c8 * 8] =
                *(const uint4*)(Ob + (size_t)(row0 + r) * 1024 + kt * 128 + c8 * 8);
        }
#pragma unroll
        for (int i = 0; i < 4; ++i) {
            int c = t + 256 * i;  int r = c >> 4, c8 = c & 15;
            *(uint4*)&lB[r * 136 + c8 * 8] =
                *(const uint4*)(wob + (size_t)(e0 + r) * 1024 + kt * 128 + c8 * 8);
        }
        __syncthreads();
        short8 a_[4];
#pragma unroll
        for (int ks = 0; ks < 4; ++ks)
            a_[ks] = *(short8*)&lA[(rt * 16 + lm) * 136 + ks * 32 + quad * 8];
#pragma unroll
        for (int ks = 0; ks < 4; ++ks)
#pragma unroll
            for (int ct = 0; ct < 2; ++ct) {
                short8 b = *(short8*)&lB[(ch * 32 + ct * 16 + lm) * 136 + ks * 32 + quad * 8];
                acc[ct] = __builtin_amdgcn_mfma_f32_16x16x32_bf16(a_[ks], b, acc[ct], 0, 0, 0);
            }
    }
    __syncthreads();
#pragma unroll
    for (int ct = 0; ct < 2; ++ct)
#pragma unroll
        for (int r = 0; r < 4; ++r)
            lCf[(rt * 16 + quad * 4 + r) * 68 + ch * 32 + ct * 16 + lm] = acc[ct][r];
    __syncthreads();
#pragma unroll
    for (int i = 0; i < 2; ++i) {
        int c = t + 256 * i;  int r = c >> 4, c4 = c & 15;
        float4 v = *(float4*)&lCf[r * 68 + c4 * 4];
        float4 b4 = *(const float4*)(bias + e0 + c4 * 4);
        v.x += b4.x; v.y += b4.y; v.z += b4.z; v.w += b4.w;
        *(float4*)(out + (size_t)(row0 + r) * 128 + e0 + c4 * 4) = v;
    }
}

// ---------------------------------------------------------------------------
extern "C" void kernel_launch(void* const* d_in, const int* in_sizes, int n_in,
                              void* d_out, int out_size, void* d_ws, size_t ws_size,
                              hipStream_t stream) {
    const float* x      = (const float*)d_in[0];
    const float* gamma  = (const float*)d_in[1];
    const float* beta   = (const float*)d_in[2];
    const float* w_qkv  = (const float*)d_in[3];
    const float* w_out  = (const float*)d_in[4];
    const float* b_out  = (const float*)d_in[5];
    float* out = (float*)d_out;
    char* wsb = (char*)d_ws;
    unsigned short* Q    = (unsigned short*)(wsb);
    unsigned short* K    = (unsigned short*)(wsb + (16ull << 20));
    unsigned short* Vt   = (unsigned short*)(wsb + (32ull << 20));
    unsigned short* Ob   = (unsigned short*)(wsb + (48ull << 20));
    unsigned short* xnb  = (unsigned short*)(wsb + (96ull << 20));
    unsigned short* wqb  = (unsigned short*)(wsb + (98ull << 20));
    unsigned short* wob  = (unsigned short*)(wsb + (99ull << 20));

    k_prep <<<dim3(2304),    256, 0, stream>>>(x, gamma, beta, w_qkv, w_out,
                                               xnb, wqb, wob);
    k_qkvf <<<dim3(64, 24),  256, 0, stream>>>(xnb, wqb, Q, K, Vt);
    k_attn <<<dim3(512),     256, 0, stream>>>(Q, K, Vt, Ob);
    k_proj <<<dim3(256, 2),  256, 0, stream>>>(Ob, wob, b_out, out);
}